// Round 12
// baseline (1436.734 us; speedup 1.0000x reference)
//
#include <hip/hip_runtime.h>

typedef float f32x4 __attribute__((ext_vector_type(4)));
typedef __bf16 bf16x8 __attribute__((ext_vector_type(8)));
typedef __bf16 bf16x4 __attribute__((ext_vector_type(4)));
typedef unsigned int u32x4 __attribute__((ext_vector_type(4)));

#define DI __device__ __forceinline__

constexpr int B_ = 4, T_ = 2048, C_ = 2048, H_ = 32;
constexpr int M_ = B_ * T_;  // 8192 rows

DI unsigned short f2bf(float f) {
  unsigned u = __float_as_uint(f);
  return (unsigned short)((u + 0x7FFFu + ((u >> 16) & 1u)) >> 16);
}
DI float bf2f(unsigned short h) { return __uint_as_float(((unsigned)h) << 16); }

DI void gl16(const void* g, void* l) {
  __builtin_amdgcn_global_load_lds(
      (__attribute__((address_space(1))) const unsigned int*)g,
      (__attribute__((address_space(3))) unsigned int*)l, 16, 0, 0);
}
DI void gl4(const void* g, void* l) {
  __builtin_amdgcn_global_load_lds(
      (__attribute__((address_space(1))) const unsigned int*)g,
      (__attribute__((address_space(3))) unsigned int*)l, 4, 0, 0);
}

// 16-lane sum, pure DPP (R4-proven): quad_perm(xor1), quad_perm(xor2),
// row_ror:4, row_ror:8 -> all 16 lanes of each aligned group get the total.
DI float rsum16(float x) {
  int t = __builtin_amdgcn_update_dpp(0, __float_as_int(x), 0xB1, 0xF, 0xF, true);
  x += __int_as_float(t);
  t = __builtin_amdgcn_update_dpp(0, __float_as_int(x), 0x4E, 0xF, 0xF, true);
  x += __int_as_float(t);
  t = __builtin_amdgcn_update_dpp(0, __float_as_int(x), 0x124, 0xF, 0xF, true);
  x += __int_as_float(t);
  t = __builtin_amdgcn_update_dpp(0, __float_as_int(x), 0x128, 0xF, 0xF, true);
  x += __int_as_float(t);
  return x;
}

// ---------------- transpose f32 (R x C) -> bf16 (C x R) ----------------
DI void tr_body(const float* __restrict__ in, unsigned short* __restrict__ out,
                int R, int C, int bx, int by, float (*tile)[33]) {
  int c0 = bx * 32, r0 = by * 32;
  int tx = threadIdx.x & 31, ty = threadIdx.x >> 5;
#pragma unroll
  for (int i = 0; i < 4; ++i) {
    int r = r0 + ty * 4 + i, c = c0 + tx;
    if (r < R && c < C) tile[ty * 4 + i][tx] = in[(size_t)r * C + c];
  }
  __syncthreads();
#pragma unroll
  for (int i = 0; i < 4; ++i) {
    int c = c0 + ty * 4 + i, r = r0 + tx;
    if (r < R && c < C) out[(size_t)c * R + r] = f2bf(tile[tx][ty * 4 + i]);
  }
}

__global__ __launch_bounds__(256) void k_transpose(const float* __restrict__ in,
                                                   unsigned short* __restrict__ out,
                                                   int R, int C) {
  __shared__ float tile[32][33];
  tr_body(in, out, R, C, blockIdx.x, blockIdx.y, tile);
}

// all 8 small weight transposes in one launch (1152 blocks)
__global__ __launch_bounds__(256) void k_transpose8(
    const float* w1, unsigned short* W1T, const float* a1, unsigned short* A1T,
    const float* v1, unsigned short* V1T, const float* g1, unsigned short* G1T,
    const float* w2, unsigned short* W2T, const float* a2, unsigned short* A2T,
    const float* v2, unsigned short* V2T, const float* g2, unsigned short* G2T) {
  __shared__ float tile[32][33];
  int b = blockIdx.x;
  if (b < 128)       tr_body(w1, W1T, 2048, 64, b % 2, b / 2, tile);
  else if (b < 256)  { b -= 128; tr_body(a1, A1T, 2048, 64, b % 2, b / 2, tile); }
  else if (b < 320)  { b -= 256; tr_body(v1, V1T, 2048, 32, 0, b, tile); }
  else if (b < 576)  { b -= 320; tr_body(g1, G1T, 2048, 128, b % 4, b / 4, tile); }
  else if (b < 704)  { b -= 576; tr_body(w2, W2T, 64, 2048, b % 64, b / 64, tile); }
  else if (b < 832)  { b -= 704; tr_body(a2, A2T, 64, 2048, b % 64, b / 64, tile); }
  else if (b < 896)  { b -= 832; tr_body(v2, V2T, 32, 2048, b % 64, b / 64, tile); }
  else               { b -= 896; tr_body(g2, G2T, 128, 2048, b % 64, b / 64, tile); }
}

// ---------------- token-shift mix prep: all 6 coef sets, x read once ----------
DI void mix_emit(const float* coef, int c0, size_t off,
                 const float* xv, const float* dx, unsigned short* dst) {
  unsigned short u[8];
#pragma unroll
  for (int i = 0; i < 2; ++i) {
    f32x4 cf = *(const f32x4*)(coef + c0 + i * 4);
#pragma unroll
    for (int j = 0; j < 4; ++j) u[i * 4 + j] = f2bf(xv[i * 4 + j] + dx[i * 4 + j] * cf[j]);
  }
  u32x4 pv;
#pragma unroll
  for (int j = 0; j < 4; ++j) pv[j] = (unsigned)u[2 * j] | ((unsigned)u[2 * j + 1] << 16);
  *(u32x4*)(dst + off) = pv;
}

__global__ __launch_bounds__(256) void k_prep6(
    const float* __restrict__ x, const float* __restrict__ xprev,
    const float* __restrict__ cR, const float* __restrict__ cV,
    const float* __restrict__ cK, const float* __restrict__ cW,
    const float* __restrict__ cA, const float* __restrict__ cG,
    unsigned short* __restrict__ XR, unsigned short* __restrict__ XV,
    unsigned short* __restrict__ XK, unsigned short* __restrict__ XW,
    unsigned short* __restrict__ XA, unsigned short* __restrict__ XG) {
  int bt = blockIdx.x;
  int t = bt & (T_ - 1);
  int c0 = threadIdx.x * 8;
  size_t off = (size_t)bt * C_ + c0;
  const float* xp = x + off;
  const float* pp = t ? (xp - C_) : (xprev + (size_t)(bt >> 11) * C_ + c0);
  float xv[8], dx[8];
#pragma unroll
  for (int i = 0; i < 2; ++i) {
    f32x4 a = *(const f32x4*)(xp + i * 4);
    f32x4 p = *(const f32x4*)(pp + i * 4);
#pragma unroll
    for (int j = 0; j < 4; ++j) { xv[i * 4 + j] = a[j]; dx[i * 4 + j] = p[j] - a[j]; }
  }
  mix_emit(cR, c0, off, xv, dx, XR);
  mix_emit(cV, c0, off, xv, dx, XV);
  mix_emit(cK, c0, off, xv, dx, XK);
  mix_emit(cW, c0, off, xv, dx, XW);
  mix_emit(cA, c0, off, xv, dx, XA);
  mix_emit(cG, c0, off, xv, dx, XG);
}

// ---------------- big GEMM: 128x128 tile, K=2048, XCD-swizzled 1D grid ----------
// EPI 0: RB = bf16(acc)
// EPI 1: VB = bf16(acc + (vfirst - acc)*svb)
// EPI 2: kk-norm fused: KB, AHB, BHB
// EPI 3: f32 store (final output GEMM)
template <int EPI>
__global__ __launch_bounds__(256, 2) void k_gemm_big(
    const unsigned short* __restrict__ A,
    const unsigned short* __restrict__ Bt,
    float* __restrict__ outF, unsigned short* __restrict__ outB,
    const unsigned short* __restrict__ svb, const float* __restrict__ vfirst,
    const unsigned short* __restrict__ abf,
    const float* __restrict__ k_k, const float* __restrict__ k_a,
    unsigned short* __restrict__ ahb, unsigned short* __restrict__ bhb) {
  __shared__ __align__(16) unsigned short As[128][64];
  __shared__ __align__(16) unsigned short Bs[128][64];
  const int tid = threadIdx.x, lane = tid & 63, wv = tid >> 6;
  const int bid = blockIdx.x;
  const int loc = bid >> 3;
  const int by = (bid & 7) * 8 + (loc & 7);
  const int bx = loc >> 3;
  const int m0 = by * 128, n0 = bx * 128;
  const int wm = (wv >> 1) * 64, wn = (wv & 1) * 64;
  const int lr = lane >> 3, lc = (lane & 7) * 8;
  f32x4 acc[4][4] = {};
  for (int kt = 0; kt < C_; kt += 64) {
    __syncthreads();
#pragma unroll
    for (int i = 0; i < 4; ++i) {
      int chunk = wv * 4 + i, r = chunk * 8 + lr;
      gl16(A + (size_t)(m0 + r) * C_ + kt + lc, (char*)&As[0][0] + chunk * 1024);
      gl16(Bt + (size_t)(n0 + r) * C_ + kt + lc, (char*)&Bs[0][0] + chunk * 1024);
    }
    __syncthreads();
    const int rr = lane & 15;
#pragma unroll
    for (int kh = 0; kh < 2; ++kh) {
      const int kof = kh * 32 + (lane >> 4) * 8;
      bf16x8 af[4], bfv[4];
#pragma unroll
      for (int i = 0; i < 4; ++i) af[i] = *(const bf16x8*)&As[wm + i * 16 + rr][kof];
#pragma unroll
      for (int j = 0; j < 4; ++j) bfv[j] = *(const bf16x8*)&Bs[wn + j * 16 + rr][kof];
#pragma unroll
      for (int i = 0; i < 4; ++i)
#pragma unroll
        for (int j = 0; j < 4; ++j)
          acc[i][j] = __builtin_amdgcn_mfma_f32_16x16x32_bf16(af[i], bfv[j], acc[i][j], 0, 0, 0);
    }
  }
  const int cr = (lane >> 4) * 4, cc2 = lane & 15;
  if constexpr (EPI == 2) {
    float kkv[4], kav[4];
#pragma unroll
    for (int j = 0; j < 4; ++j) {
      int col = n0 + wn + j * 16 + cc2;
      kkv[j] = k_k[col];
      kav[j] = k_a[col];
    }
#pragma unroll
    for (int i = 0; i < 4; ++i)
#pragma unroll
      for (int q = 0; q < 4; ++q) {
        int row = m0 + wm + i * 16 + cr + q;
        float kk4[4], p = 0.f;
#pragma unroll
        for (int j = 0; j < 4; ++j) {
          float kkc = acc[i][j][q] * kkv[j];
          kk4[j] = kkc;
          p += kkc * kkc;
        }
        p += __shfl_xor(p, 1); p += __shfl_xor(p, 2);
        p += __shfl_xor(p, 4); p += __shfl_xor(p, 8);
        float inv = 1.f / fmaxf(sqrtf(p), 1e-12f);
#pragma unroll
        for (int j = 0; j < 4; ++j) {
          int col = n0 + wn + j * 16 + cc2;
          size_t off = (size_t)row * C_ + col;
          float kkn = kk4[j] * inv;
          float a = bf2f(abf[off]);
          ahb[off] = f2bf(-kkn);
          bhb[off] = f2bf(kkn * a);
          outB[off] = f2bf(acc[i][j][q] * (1.f + (a - 1.f) * kav[j]));
        }
      }
  } else {
#pragma unroll
    for (int i = 0; i < 4; ++i)
#pragma unroll
      for (int j = 0; j < 4; ++j)
#pragma unroll
        for (int q = 0; q < 4; ++q) {
          int row = m0 + wm + i * 16 + cr + q;
          int col = n0 + wn + j * 16 + cc2;
          size_t off = (size_t)row * C_ + col;
          float v = acc[i][j][q];
          if constexpr (EPI == 0) {
            outB[off] = f2bf(v);
          } else if constexpr (EPI == 1) {
            float s = bf2f(svb[off]);
            outB[off] = f2bf(v + (vfirst[off] - v) * s);
          } else {
            outF[off] = v;
          }
        }
  }
}

// ---------------- down GEMM body (plain bf16 A staging) ----------------
template <int N, int ACT>
DI void down_body(int m0, unsigned short (*As)[64], unsigned short (*Bs)[64],
                  const unsigned short* __restrict__ A,
                  const unsigned short* __restrict__ Bt,
                  unsigned short* __restrict__ out) {
  const int tid = threadIdx.x, lane = tid & 63, wv = tid >> 6;
  const int wm = wv * 32;
  const int lr = lane >> 3, lc = (lane & 7) * 8;
  f32x4 acc[2][N / 16] = {};
  for (int kt = 0; kt < C_; kt += 64) {
    __syncthreads();
#pragma unroll
    for (int i = 0; i < 4; ++i) {
      int chunk = wv * 4 + i, r = chunk * 8 + lr;
      gl16(A + (size_t)(m0 + r) * C_ + kt + lc, (char*)&As[0][0] + chunk * 1024);
    }
#pragma unroll
    for (int i = 0; i < N / 32; ++i) {
      int chunk = wv * (N / 32) + i, r = chunk * 8 + lr;
      gl16(Bt + (size_t)r * C_ + kt + lc, (char*)&Bs[0][0] + chunk * 1024);
    }
    __syncthreads();
    const int rr = lane & 15;
#pragma unroll
    for (int kh = 0; kh < 2; ++kh) {
      const int kof = kh * 32 + (lane >> 4) * 8;
      bf16x8 af[2], bfv[N / 16];
#pragma unroll
      for (int i = 0; i < 2; ++i) af[i] = *(const bf16x8*)&As[wm + i * 16 + rr][kof];
#pragma unroll
      for (int j = 0; j < N / 16; ++j) bfv[j] = *(const bf16x8*)&Bs[j * 16 + rr][kof];
#pragma unroll
      for (int i = 0; i < 2; ++i)
#pragma unroll
        for (int j = 0; j < N / 16; ++j)
          acc[i][j] = __builtin_amdgcn_mfma_f32_16x16x32_bf16(af[i], bfv[j], acc[i][j], 0, 0, 0);
    }
  }
  const int cr = (lane >> 4) * 4, cc2 = lane & 15;
#pragma unroll
  for (int i = 0; i < 2; ++i)
#pragma unroll
    for (int j = 0; j < N / 16; ++j)
#pragma unroll
      for (int q = 0; q < 4; ++q) {
        int row = m0 + wm + i * 16 + cr + q;
        int col = j * 16 + cc2;
        float v = acc[i][j][q];
        if (ACT == 1) v = tanhf(v);
        else if (ACT == 2) v = 1.f / (1.f + expf(-v));
        out[(size_t)row * N + col] = f2bf(v);
      }
}

// merged down-GEMMs: 256 blocks (4 groups x 64 m-tiles), all prepacked mixes
__global__ __launch_bounds__(256, 2) void k_down4(
    const unsigned short* __restrict__ XMw, const unsigned short* __restrict__ XMa,
    const unsigned short* __restrict__ XMv, const unsigned short* __restrict__ XMg,
    const unsigned short* __restrict__ W1T, const unsigned short* __restrict__ A1T,
    const unsigned short* __restrict__ V1T, const unsigned short* __restrict__ G1T,
    unsigned short* __restrict__ HWB, unsigned short* __restrict__ HAB,
    unsigned short* __restrict__ HVB, unsigned short* __restrict__ HGB) {
  __shared__ __align__(16) unsigned short As[128][64];
  __shared__ __align__(16) unsigned short Bs[128][64];
  int g = blockIdx.x >> 6;
  int m0 = (blockIdx.x & 63) * 128;
  if (g == 0)      down_body<64, 1>(m0, As, Bs, XMw, W1T, HWB);
  else if (g == 1) down_body<64, 0>(m0, As, Bs, XMa, A1T, HAB);
  else if (g == 2) down_body<32, 0>(m0, As, Bs, XMv, V1T, HVB);
  else             down_body<128, 2>(m0, As, Bs, XMg, G1T, HGB);
}

// ---------------- up GEMM (K in {32,64,128}), single K pass ----------------
// MODE 0: wd = exp(-exp(-softplus(-(bias+up)) - 0.5)) -> outF (f32)
// MODE 1: sigmoid(bias+up) -> outB (bf16)
// MODE 3: up -> outB (bf16)
template <int K, int MODE>
__global__ __launch_bounds__(256, 2) void k_up(
    const unsigned short* __restrict__ A, const unsigned short* __restrict__ Bt,
    const float* __restrict__ bias, float* __restrict__ outF,
    unsigned short* __restrict__ outB) {
  __shared__ __align__(16) unsigned short As[128][K];
  __shared__ __align__(16) unsigned short Bs[128][K];
  const int tid = threadIdx.x, lane = tid & 63, wv = tid >> 6;
  const int m0 = blockIdx.y * 128, n0 = blockIdx.x * 128;
  const int wm = (wv >> 1) * 64, wn = (wv & 1) * 64;
  constexpr int LPR = K / 8;
  constexpr int RPC = 64 / LPR;
  const int lr = lane / LPR, lc = (lane % LPR) * 8;
  f32x4 acc[4][4] = {};
#pragma unroll
  for (int i = 0; i < K / 16; ++i) {
    int chunk = wv * (K / 16) + i;
    int r = chunk * RPC + lr;
    gl16(A + (size_t)(m0 + r) * K + lc, (char*)&As[0][0] + chunk * 1024);
    gl16(Bt + (size_t)(n0 + r) * K + lc, (char*)&Bs[0][0] + chunk * 1024);
  }
  __syncthreads();
  const int rr = lane & 15;
#pragma unroll
  for (int ks = 0; ks < K / 32; ++ks) {
    const int kof = ks * 32 + (lane >> 4) * 8;
    bf16x8 af[4], bfv[4];
#pragma unroll
    for (int i = 0; i < 4; ++i) af[i] = *(const bf16x8*)&As[wm + i * 16 + rr][kof];
#pragma unroll
    for (int j = 0; j < 4; ++j) bfv[j] = *(const bf16x8*)&Bs[wn + j * 16 + rr][kof];
#pragma unroll
    for (int i = 0; i < 4; ++i)
#pragma unroll
      for (int j = 0; j < 4; ++j)
        acc[i][j] = __builtin_amdgcn_mfma_f32_16x16x32_bf16(af[i], bfv[j], acc[i][j], 0, 0, 0);
  }
  const int cr = (lane >> 4) * 4, cc2 = lane & 15;
#pragma unroll
  for (int i = 0; i < 4; ++i)
#pragma unroll
    for (int j = 0; j < 4; ++j)
#pragma unroll
      for (int q = 0; q < 4; ++q) {
        int row = m0 + wm + i * 16 + cr + q;
        int col = n0 + wn + j * 16 + cc2;
        size_t off = (size_t)row * C_ + col;
        float up = acc[i][j][q];
        if (MODE == 0) {
          float z = -(bias[col] + up);
          float sp = fmaxf(z, 0.f) + log1pf(expf(-fabsf(z)));
          outF[off] = expf(-expf(-sp - 0.5f));
        } else if (MODE == 1) {
          outB[off] = f2bf(1.f / (1.f + expf(-(bias[col] + up))));
        } else {
          outB[off] = f2bf(up);
        }
      }
}

// ---------------- WKV recurrent scan: LDS-pipelined, 2 waves/SIMD --------------
// R11 structure with the vmcnt-store bug fixed. 2048 one-wave blocks, 4 rows/
// wave. The per-step global store ALSO increments vmcnt: steady-state queue at
// each STEP wait is [L_t x4, S_{t-4}, L_{t+1} x4, S_{t-3}, ..., L_{t+4} x4] =
// 24 ops, so vmcnt(16) (R11) drained 4 loads + 4 stores incl. S_{t-1} (~200-300
// cyc store-ack on the critical path every step). Correct wait: vmcnt(20) in
// steady state (drains exactly the 4 current-slot loads); peel t=0..3 with
// 16/17/18/19 (queue holds 0/1/2/3 stores there). Runtime slot index is LDS
// address arithmetic only (no register-file indexing).
__global__ __launch_bounds__(64) void k_scan(
    const unsigned short* __restrict__ RB, const float* __restrict__ WD,
    const unsigned short* __restrict__ KB, const unsigned short* __restrict__ VB,
    const unsigned short* __restrict__ AHB, const unsigned short* __restrict__ BHB,
    const float* __restrict__ s0, float* __restrict__ out) {
  __shared__ __align__(16) char sl[8][1024];
  const int lane = threadIdx.x & 63;
  const int p = blockIdx.x;
  const int wq = p >> 7, bh = p & 127;
  const int b = bh >> 5, h = bh & 31;
  const int e = lane & 15, rl = lane >> 4;
  const int row = wq * 4 + rl;
  const size_t base = (size_t)b * T_ * C_ + h * 64;
  f32x4 S = *(const f32x4*)(s0 + ((size_t)(b * H_ + h) * 64 + row) * 64 + e * 4);

#define SWAIT_(n) asm volatile("s_waitcnt vmcnt(" #n ")" ::: "memory")
#define SWAIT(n) SWAIT_(n)

#define ISSUE(t, slot)                                                        \
  {                                                                           \
    int ti = (t) < T_ ? (t) : T_ - 1;                                         \
    size_t eo = base + (size_t)ti * C_;                                       \
    char* d = &sl[(slot)][0];                                                 \
    const char* s1 = lane < 32 ? (const char*)(RB + eo) + lane * 4            \
                               : (const char*)(KB + eo) + (lane - 32) * 4;    \
    gl4(s1, d);                                                               \
    const char* s2 = lane < 32 ? (const char*)(AHB + eo) + lane * 4           \
                               : (const char*)(BHB + eo) + (lane - 32) * 4;   \
    gl4(s2, d + 256);                                                         \
    gl4((const char*)(WD + eo) + lane * 4, d + 512);                          \
    gl4((const char*)(VB + eo) + lane * 4, d + 768);                          \
  }

#define STEP(t, slot, VM)                                                     \
  {                                                                           \
    SWAIT(VM);                                                                \
    __builtin_amdgcn_sched_barrier(0);                                        \
    const char* bp = &sl[(slot)][0];                                          \
    bf16x4 rv = *(const bf16x4*)(bp + e * 8);                                 \
    bf16x4 kv = *(const bf16x4*)(bp + 128 + e * 8);                           \
    bf16x4 av = *(const bf16x4*)(bp + 256 + e * 8);                           \
    bf16x4 bv4 = *(const bf16x4*)(bp + 384 + e * 8);                          \
    f32x4 wv = *(const f32x4*)(bp + 512 + e * 16);                            \
    float vi = bf2f(*(const unsigned short*)(bp + 768 + row * 2));            \
    float rr[4], kk[4], aa[4], bb[4];                                         \
    _Pragma("unroll") for (int j = 0; j < 4; ++j) {                           \
      rr[j] = (float)rv[j];                                                   \
      kk[j] = (float)kv[j];                                                   \
      aa[j] = (float)av[j];                                                   \
      bb[j] = (float)bv4[j];                                                  \
    }                                                                         \
    float sa = S[0] * aa[0];                                                  \
    sa = fmaf(S[1], aa[1], sa);                                               \
    sa = fmaf(S[2], aa[2], sa);                                               \
    sa = fmaf(S[3], aa[3], sa);                                               \
    sa = rsum16(sa);                                                          \
    float o = 0.f;                                                            \
    _Pragma("unroll") for (int j = 0; j < 4; ++j) {                           \
      S[j] = fmaf(S[j], wv[j], fmaf(sa, bb[j], vi * kk[j]));                  \
      o = fmaf(S[j], rr[j], o);                                               \
    }                                                                         \
    o = rsum16(o);                                                            \
    if (e == 0) out[base + (size_t)(t) * C_ + row] = o;                       \
  }

  ISSUE(0, 0) ISSUE(1, 1) ISSUE(2, 2) ISSUE(3, 3)
  // peeled steps: queue holds 0/1/2/3 stores -> exact waits
  ISSUE(4, 4) STEP(0, 0, 16)
  ISSUE(5, 5) STEP(1, 1, 17)
  ISSUE(6, 6) STEP(2, 2, 18)
  ISSUE(7, 7) STEP(3, 3, 19)
#pragma unroll 1
  for (int t = 4; t < T_; t += 4) {
    ISSUE(t + 4, (t + 4) & 7) STEP(t, t & 7, 20)
    ISSUE(t + 5, (t + 5) & 7) STEP(t + 1, (t + 1) & 7, 20)
    ISSUE(t + 6, (t + 6) & 7) STEP(t + 2, (t + 2) & 7, 20)
    ISSUE(t + 7, (t + 7) & 7) STEP(t + 3, (t + 3) & 7, 20)
  }
#undef ISSUE
#undef STEP
#undef SWAIT
#undef SWAIT_
}

// ---------------- GroupNorm + bonus + gate (wave per (b,t,h)) ----------------
__global__ __launch_bounds__(256) void k_gn(
    const float* __restrict__ o, const unsigned short* __restrict__ rb,
    const unsigned short* __restrict__ kb, const unsigned short* __restrict__ v,
    const unsigned short* __restrict__ g, const float* __restrict__ r_k,
    const float* __restrict__ lnw, const float* __restrict__ lnb,
    unsigned short* __restrict__ outg) {
  int wid = blockIdx.x * 4 + (threadIdx.x >> 6);
  int lane = threadIdx.x & 63;
  int h = wid & (H_ - 1);
  size_t bt = (size_t)(wid >> 5);
  size_t off = bt * C_ + h * 64 + lane;
  int c = h * 64 + lane;
  float x = o[off];
  float mu = x;
#pragma unroll
  for (int m = 1; m < 64; m <<= 1) mu += __shfl_xor(mu, m);
  mu *= (1.f / 64.f);
  float d = x - mu;
  float var = d * d;
#pragma unroll
  for (int m = 1; m < 64; m <<= 1) var += __shfl_xor(var, m);
  var *= (1.f / 64.f);
  float y = d * rsqrtf(var + 6.4e-4f) * lnw[c] + lnb[c];
  float bd = bf2f(rb[off]) * bf2f(kb[off]) * r_k[c];
#pragma unroll
  for (int m = 1; m < 64; m <<= 1) bd += __shfl_xor(bd, m);
  float res = (y + bd * bf2f(v[off])) * bf2f(g[off]);
  outg[off] = f2bf(res);
}

// ---------------- host launch ----------------
extern "C" void kernel_launch(void* const* d_in, const int* in_sizes, int n_in,
                              void* d_out, int out_size, void* d_ws, size_t ws_size,
                              hipStream_t stream) {
  const float* x      = (const float*)d_in[0];
  const float* vfirst = (const float*)d_in[1];
  const float* xprev  = (const float*)d_in[2];
  const float* wkv0   = (const float*)d_in[3];
  const float* x_r = (const float*)d_in[4];
  const float* x_w = (const float*)d_in[5];
  const float* x_k = (const float*)d_in[6];
  const float* x_v = (const float*)d_in[7];
  const float* x_a = (const float*)d_in[8];
  const float* x_g = (const float*)d_in[9];
  const float* w0 = (const float*)d_in[10];
  const float* w1 = (const float*)d_in[11];
  const float* w2 = (const float*)d_in[12];
  const float* a0 = (const float*)d_in[13];
  const float* a1 = (const float*)d_in[14];
  const float* a2 = (const float*)d_in[15];
  const float* v0 = (const float*)d_in[16];
  const float* v1 = (const float*)d_in[17];
  const float* v2 = (const float*)d_in[18];
  const float* g1 = (const float*)d_in[19];
  const float* g2 = (const float*)d_in[20];
  const float* k_k = (const float*)d_in[21];
  const float* k_a = (const float*)d_in[22];
  const float* r_k = (const float*)d_in[23];
  const float* Wr = (const float*)d_in[24];
  const float* Wk = (const float*)d_in[25];
  const float* Wv = (const float*)d_in[26];
  const float* Wo = (const float*)d_in[27];
  const float* lnw = (const float*)d_in[28];
  const float* lnb = (const float*)d_in[29];
  float* out = (float*)d_out;
  char* ws = (char*)d_ws;

  // ---- workspace layout (~239 MiB + pad) ----
  size_t woff = 0;
  auto alloc = [&](size_t n) { char* p = ws + woff; woff += n; return p; };
  char* R1 = alloc(67108864);                       // ABF|SVB -> WD (f32)
  unsigned short* ABF = (unsigned short*)R1;
  unsigned short* SVB = (unsigned short*)(R1 + 33554432);
  float* WD = (float*)R1;
  unsigned short* WT  = (unsigned short*)alloc(8388608);   // transposed big weight
  unsigned short* W1T = (unsigned short*)alloc(262144);
  unsigned short* A1T = (unsigned short*)alloc(262144);
  unsigned short* V1T = (unsigned short*)alloc(131072);
  unsigned short* G1T = (unsigned short*)alloc(524288);
  unsigned short* W2T = (unsigned short*)alloc(262144);
  unsigned short* A2T = (unsigned short*)alloc(262144);
  unsigned short* V2T = (unsigned short*)alloc(131072);
  unsigned short* G2T = (unsigned short*)alloc(524288);
  unsigned short* HWB = (unsigned short*)alloc(1048576);
  unsigned short* HAB = (unsigned short*)alloc(1048576);
  unsigned short* HVB = (unsigned short*)alloc(524288);
  unsigned short* HGB = (unsigned short*)alloc(2097152);
  unsigned short* RB  = (unsigned short*)alloc(33554432);
  unsigned short* KB  = (unsigned short*)alloc(33554432);
  unsigned short* VB  = (unsigned short*)alloc(33554432);
  unsigned short* AHB = (unsigned short*)alloc(33554432);
  unsigned short* BHB = (unsigned short*)alloc(33554432);
  alloc(65536);  // safety pad (scan prefetch over-read)
  // Temporal overlays (regions dead at the time of each use):
  unsigned short* XMr = VB;                   // dead once V-GEMM writes VB
  unsigned short* XMv = KB;                   // dead once K-GEMM writes KB
  unsigned short* XMk = (unsigned short*)out; // d_out free until scan writes out
  unsigned short* XMw = AHB;                  // dead once K-GEMM writes AHB (down4 done)
  unsigned short* XMa = BHB;                  // dead once K-GEMM writes BHB (down4 done)
  unsigned short* XMg = RB;                   // dead once R-GEMM writes RB (down4 done)
  unsigned short* GBF  = AHB;                 // post-scan overlay (AHB dead)
  unsigned short* OUTG = BHB;                 // post-scan overlay (BHB dead)

  dim3 blk(256);
  dim3 gg(16, 64);
  dim3 g1d(1024);

  // all small weight transposes in one launch
  k_transpose8<<<dim3(1152), blk, 0, stream>>>(w1, W1T, a1, A1T, v1, V1T, g1, G1T,
                                               w2, W2T, a2, A2T, v2, V2T, g2, G2T);

  // mix prep: x read once -> all 6 mixes (XMk in d_out, XMw/XMa/XMg overlays)
  k_prep6<<<dim3(M_), blk, 0, stream>>>(x, xprev, x_r, x_v, x_k, x_w, x_a, x_g,
                                        XMr, XMv, XMk, XMw, XMa, XMg);

  // merged down-GEMMs (w,a,v,g), all prepacked bf16 mixes
  k_down4<<<dim3(256), blk, 0, stream>>>(XMw, XMa, XMv, XMg,
                                         W1T, A1T, V1T, G1T, HWB, HAB, HVB, HGB);

  // up-GEMMs needed before projections
  k_up<64, 1><<<gg, blk, 0, stream>>>(HAB, A2T, a0, nullptr, ABF);
  k_up<32, 1><<<gg, blk, 0, stream>>>(HVB, V2T, v0, nullptr, SVB);

  // R projection (XMr in VB region; writes RB, killing XMg)
  k_transpose<<<dim3(64, 64), blk, 0, stream>>>(Wr, WT, 2048, 2048);
  k_gemm_big<0><<<g1d, blk, 0, stream>>>(XMr, WT,
      nullptr, RB, nullptr, nullptr, nullptr, nullptr, nullptr, nullptr, nullptr);

  // V projection (reads XMv from KB region + SVB; writes VB, killing XMr)
  k_transpose<<<dim3(64, 64), blk, 0, stream>>>(Wv, WT, 2048, 2048);
  k_gemm_big<1><<<g1d, blk, 0, stream>>>(XMv, WT,
      nullptr, VB, SVB, vfirst, nullptr, nullptr, nullptr, nullptr, nullptr);

  // K projection (reads XMk from d_out; writes KB killing XMv, AHB killing XMw,
  // BHB killing XMa)
  k_transpose<<<dim3(64, 64), blk, 0, stream>>>(Wk, WT, 2048, 2048);
  k_gemm_big<2><<<g1d, blk, 0, stream>>>(XMk, WT,
      nullptr, KB, nullptr, nullptr, ABF, k_k, k_a, AHB, BHB);

  // w-chain up (WD overlays ABF+SVB, both consumed)
  k_up<64, 0><<<gg, blk, 0, stream>>>(HWB, W2T, w0, WD, nullptr);

  // recurrent scan -> out[b,t,c] f32 in d_out (XMk already consumed)
  k_scan<<<dim3(2048), dim3(64), 0, stream>>>(RB, WD, KB, VB, AHB, BHB, wkv0, out);

  // g-chain up (GBF overlays AHB)
  k_up<128, 3><<<gg, blk, 0, stream>>>(HGB, G2T, nullptr, nullptr, GBF);

  // GroupNorm + bonus + gate (OUTG overlays BHB)
  k_gn<<<dim3(65536), blk, 0, stream>>>(out, RB, KB, VB, GBF, r_k, lnw, lnb, OUTG);

  // final projection (overwrites d_out with the real output)
  k_transpose<<<dim3(64, 64), blk, 0, stream>>>(Wo, WT, 2048, 2048);
  k_gemm_big<3><<<g1d, blk, 0, stream>>>(OUTG, WT,
      out, nullptr, nullptr, nullptr, nullptr, nullptr, nullptr, nullptr, nullptr);
}

// Round 13
// 1281.568 us; speedup vs baseline: 1.1211x; 1.1211x over previous
//
#include <hip/hip_runtime.h>

typedef float f32x4 __attribute__((ext_vector_type(4)));
typedef __bf16 bf16x8 __attribute__((ext_vector_type(8)));
typedef __bf16 bf16x4 __attribute__((ext_vector_type(4)));
typedef unsigned int u32x4 __attribute__((ext_vector_type(4)));

#define DI __device__ __forceinline__

constexpr int B_ = 4, T_ = 2048, C_ = 2048, H_ = 32;
constexpr int M_ = B_ * T_;  // 8192 rows

DI unsigned short f2bf(float f) {
  unsigned u = __float_as_uint(f);
  return (unsigned short)((u + 0x7FFFu + ((u >> 16) & 1u)) >> 16);
}
DI float bf2f(unsigned short h) { return __uint_as_float(((unsigned)h) << 16); }

DI void gl16(const void* g, void* l) {
  __builtin_amdgcn_global_load_lds(
      (__attribute__((address_space(1))) const unsigned int*)g,
      (__attribute__((address_space(3))) unsigned int*)l, 16, 0, 0);
}
DI void gl4(const void* g, void* l) {
  __builtin_amdgcn_global_load_lds(
      (__attribute__((address_space(1))) const unsigned int*)g,
      (__attribute__((address_space(3))) unsigned int*)l, 4, 0, 0);
}

// 16-lane sum, pure DPP (R4-proven): quad_perm(xor1), quad_perm(xor2),
// row_ror:4, row_ror:8 -> all 16 lanes of each aligned group get the total.
DI float rsum16(float x) {
  int t = __builtin_amdgcn_update_dpp(0, __float_as_int(x), 0xB1, 0xF, 0xF, true);
  x += __int_as_float(t);
  t = __builtin_amdgcn_update_dpp(0, __float_as_int(x), 0x4E, 0xF, 0xF, true);
  x += __int_as_float(t);
  t = __builtin_amdgcn_update_dpp(0, __float_as_int(x), 0x124, 0xF, 0xF, true);
  x += __int_as_float(t);
  t = __builtin_amdgcn_update_dpp(0, __float_as_int(x), 0x128, 0xF, 0xF, true);
  x += __int_as_float(t);
  return x;
}

// ---------------- transpose f32 (R x C) -> bf16 (C x R) ----------------
DI void tr_body(const float* __restrict__ in, unsigned short* __restrict__ out,
                int R, int C, int bx, int by, float (*tile)[33]) {
  int c0 = bx * 32, r0 = by * 32;
  int tx = threadIdx.x & 31, ty = threadIdx.x >> 5;
#pragma unroll
  for (int i = 0; i < 4; ++i) {
    int r = r0 + ty * 4 + i, c = c0 + tx;
    if (r < R && c < C) tile[ty * 4 + i][tx] = in[(size_t)r * C + c];
  }
  __syncthreads();
#pragma unroll
  for (int i = 0; i < 4; ++i) {
    int c = c0 + ty * 4 + i, r = r0 + tx;
    if (r < R && c < C) out[(size_t)c * R + r] = f2bf(tile[tx][ty * 4 + i]);
  }
}

__global__ __launch_bounds__(256) void k_transpose(const float* __restrict__ in,
                                                   unsigned short* __restrict__ out,
                                                   int R, int C) {
  __shared__ float tile[32][33];
  tr_body(in, out, R, C, blockIdx.x, blockIdx.y, tile);
}

// all 8 small weight transposes in one launch (1152 blocks)
__global__ __launch_bounds__(256) void k_transpose8(
    const float* w1, unsigned short* W1T, const float* a1, unsigned short* A1T,
    const float* v1, unsigned short* V1T, const float* g1, unsigned short* G1T,
    const float* w2, unsigned short* W2T, const float* a2, unsigned short* A2T,
    const float* v2, unsigned short* V2T, const float* g2, unsigned short* G2T) {
  __shared__ float tile[32][33];
  int b = blockIdx.x;
  if (b < 128)       tr_body(w1, W1T, 2048, 64, b % 2, b / 2, tile);
  else if (b < 256)  { b -= 128; tr_body(a1, A1T, 2048, 64, b % 2, b / 2, tile); }
  else if (b < 320)  { b -= 256; tr_body(v1, V1T, 2048, 32, 0, b, tile); }
  else if (b < 576)  { b -= 320; tr_body(g1, G1T, 2048, 128, b % 4, b / 4, tile); }
  else if (b < 704)  { b -= 576; tr_body(w2, W2T, 64, 2048, b % 64, b / 64, tile); }
  else if (b < 832)  { b -= 704; tr_body(a2, A2T, 64, 2048, b % 64, b / 64, tile); }
  else if (b < 896)  { b -= 832; tr_body(v2, V2T, 32, 2048, b % 64, b / 64, tile); }
  else               { b -= 896; tr_body(g2, G2T, 128, 2048, b % 64, b / 64, tile); }
}

// ---------------- token-shift mix prep: all 6 coef sets, x read once ----------
DI void mix_emit(const float* coef, int c0, size_t off,
                 const float* xv, const float* dx, unsigned short* dst) {
  unsigned short u[8];
#pragma unroll
  for (int i = 0; i < 2; ++i) {
    f32x4 cf = *(const f32x4*)(coef + c0 + i * 4);
#pragma unroll
    for (int j = 0; j < 4; ++j) u[i * 4 + j] = f2bf(xv[i * 4 + j] + dx[i * 4 + j] * cf[j]);
  }
  u32x4 pv;
#pragma unroll
  for (int j = 0; j < 4; ++j) pv[j] = (unsigned)u[2 * j] | ((unsigned)u[2 * j + 1] << 16);
  *(u32x4*)(dst + off) = pv;
}

__global__ __launch_bounds__(256) void k_prep6(
    const float* __restrict__ x, const float* __restrict__ xprev,
    const float* __restrict__ cR, const float* __restrict__ cV,
    const float* __restrict__ cK, const float* __restrict__ cW,
    const float* __restrict__ cA, const float* __restrict__ cG,
    unsigned short* __restrict__ XR, unsigned short* __restrict__ XV,
    unsigned short* __restrict__ XK, unsigned short* __restrict__ XW,
    unsigned short* __restrict__ XA, unsigned short* __restrict__ XG) {
  int bt = blockIdx.x;
  int t = bt & (T_ - 1);
  int c0 = threadIdx.x * 8;
  size_t off = (size_t)bt * C_ + c0;
  const float* xp = x + off;
  const float* pp = t ? (xp - C_) : (xprev + (size_t)(bt >> 11) * C_ + c0);
  float xv[8], dx[8];
#pragma unroll
  for (int i = 0; i < 2; ++i) {
    f32x4 a = *(const f32x4*)(xp + i * 4);
    f32x4 p = *(const f32x4*)(pp + i * 4);
#pragma unroll
    for (int j = 0; j < 4; ++j) { xv[i * 4 + j] = a[j]; dx[i * 4 + j] = p[j] - a[j]; }
  }
  mix_emit(cR, c0, off, xv, dx, XR);
  mix_emit(cV, c0, off, xv, dx, XV);
  mix_emit(cK, c0, off, xv, dx, XK);
  mix_emit(cW, c0, off, xv, dx, XW);
  mix_emit(cA, c0, off, xv, dx, XA);
  mix_emit(cG, c0, off, xv, dx, XG);
}

// ---------------- big GEMM: 128x128 tile, K=2048, XCD-swizzled 1D grid ----------
// EPI 0: RB = bf16(acc)
// EPI 1: VB = bf16(acc + (vfirst - acc)*svb)
// EPI 2: kk-norm fused: KB, AHB, BHB
// EPI 3: f32 store (final output GEMM)
template <int EPI>
__global__ __launch_bounds__(256, 2) void k_gemm_big(
    const unsigned short* __restrict__ A,
    const unsigned short* __restrict__ Bt,
    float* __restrict__ outF, unsigned short* __restrict__ outB,
    const unsigned short* __restrict__ svb, const float* __restrict__ vfirst,
    const unsigned short* __restrict__ abf,
    const float* __restrict__ k_k, const float* __restrict__ k_a,
    unsigned short* __restrict__ ahb, unsigned short* __restrict__ bhb) {
  __shared__ __align__(16) unsigned short As[128][64];
  __shared__ __align__(16) unsigned short Bs[128][64];
  const int tid = threadIdx.x, lane = tid & 63, wv = tid >> 6;
  const int bid = blockIdx.x;
  const int loc = bid >> 3;
  const int by = (bid & 7) * 8 + (loc & 7);
  const int bx = loc >> 3;
  const int m0 = by * 128, n0 = bx * 128;
  const int wm = (wv >> 1) * 64, wn = (wv & 1) * 64;
  const int lr = lane >> 3, lc = (lane & 7) * 8;
  f32x4 acc[4][4] = {};
  for (int kt = 0; kt < C_; kt += 64) {
    __syncthreads();
#pragma unroll
    for (int i = 0; i < 4; ++i) {
      int chunk = wv * 4 + i, r = chunk * 8 + lr;
      gl16(A + (size_t)(m0 + r) * C_ + kt + lc, (char*)&As[0][0] + chunk * 1024);
      gl16(Bt + (size_t)(n0 + r) * C_ + kt + lc, (char*)&Bs[0][0] + chunk * 1024);
    }
    __syncthreads();
    const int rr = lane & 15;
#pragma unroll
    for (int kh = 0; kh < 2; ++kh) {
      const int kof = kh * 32 + (lane >> 4) * 8;
      bf16x8 af[4], bfv[4];
#pragma unroll
      for (int i = 0; i < 4; ++i) af[i] = *(const bf16x8*)&As[wm + i * 16 + rr][kof];
#pragma unroll
      for (int j = 0; j < 4; ++j) bfv[j] = *(const bf16x8*)&Bs[wn + j * 16 + rr][kof];
#pragma unroll
      for (int i = 0; i < 4; ++i)
#pragma unroll
        for (int j = 0; j < 4; ++j)
          acc[i][j] = __builtin_amdgcn_mfma_f32_16x16x32_bf16(af[i], bfv[j], acc[i][j], 0, 0, 0);
    }
  }
  const int cr = (lane >> 4) * 4, cc2 = lane & 15;
  if constexpr (EPI == 2) {
    float kkv[4], kav[4];
#pragma unroll
    for (int j = 0; j < 4; ++j) {
      int col = n0 + wn + j * 16 + cc2;
      kkv[j] = k_k[col];
      kav[j] = k_a[col];
    }
#pragma unroll
    for (int i = 0; i < 4; ++i)
#pragma unroll
      for (int q = 0; q < 4; ++q) {
        int row = m0 + wm + i * 16 + cr + q;
        float kk4[4], p = 0.f;
#pragma unroll
        for (int j = 0; j < 4; ++j) {
          float kkc = acc[i][j][q] * kkv[j];
          kk4[j] = kkc;
          p += kkc * kkc;
        }
        p += __shfl_xor(p, 1); p += __shfl_xor(p, 2);
        p += __shfl_xor(p, 4); p += __shfl_xor(p, 8);
        float inv = 1.f / fmaxf(sqrtf(p), 1e-12f);
#pragma unroll
        for (int j = 0; j < 4; ++j) {
          int col = n0 + wn + j * 16 + cc2;
          size_t off = (size_t)row * C_ + col;
          float kkn = kk4[j] * inv;
          float a = bf2f(abf[off]);
          ahb[off] = f2bf(-kkn);
          bhb[off] = f2bf(kkn * a);
          outB[off] = f2bf(acc[i][j][q] * (1.f + (a - 1.f) * kav[j]));
        }
      }
  } else {
#pragma unroll
    for (int i = 0; i < 4; ++i)
#pragma unroll
      for (int j = 0; j < 4; ++j)
#pragma unroll
        for (int q = 0; q < 4; ++q) {
          int row = m0 + wm + i * 16 + cr + q;
          int col = n0 + wn + j * 16 + cc2;
          size_t off = (size_t)row * C_ + col;
          float v = acc[i][j][q];
          if constexpr (EPI == 0) {
            outB[off] = f2bf(v);
          } else if constexpr (EPI == 1) {
            float s = bf2f(svb[off]);
            outB[off] = f2bf(v + (vfirst[off] - v) * s);
          } else {
            outF[off] = v;
          }
        }
  }
}

// ---------------- down GEMM body (plain bf16 A staging) ----------------
template <int N, int ACT>
DI void down_body(int m0, unsigned short (*As)[64], unsigned short (*Bs)[64],
                  const unsigned short* __restrict__ A,
                  const unsigned short* __restrict__ Bt,
                  unsigned short* __restrict__ out) {
  const int tid = threadIdx.x, lane = tid & 63, wv = tid >> 6;
  const int wm = wv * 32;
  const int lr = lane >> 3, lc = (lane & 7) * 8;
  f32x4 acc[2][N / 16] = {};
  for (int kt = 0; kt < C_; kt += 64) {
    __syncthreads();
#pragma unroll
    for (int i = 0; i < 4; ++i) {
      int chunk = wv * 4 + i, r = chunk * 8 + lr;
      gl16(A + (size_t)(m0 + r) * C_ + kt + lc, (char*)&As[0][0] + chunk * 1024);
    }
#pragma unroll
    for (int i = 0; i < N / 32; ++i) {
      int chunk = wv * (N / 32) + i, r = chunk * 8 + lr;
      gl16(Bt + (size_t)r * C_ + kt + lc, (char*)&Bs[0][0] + chunk * 1024);
    }
    __syncthreads();
    const int rr = lane & 15;
#pragma unroll
    for (int kh = 0; kh < 2; ++kh) {
      const int kof = kh * 32 + (lane >> 4) * 8;
      bf16x8 af[2], bfv[N / 16];
#pragma unroll
      for (int i = 0; i < 2; ++i) af[i] = *(const bf16x8*)&As[wm + i * 16 + rr][kof];
#pragma unroll
      for (int j = 0; j < N / 16; ++j) bfv[j] = *(const bf16x8*)&Bs[j * 16 + rr][kof];
#pragma unroll
      for (int i = 0; i < 2; ++i)
#pragma unroll
        for (int j = 0; j < N / 16; ++j)
          acc[i][j] = __builtin_amdgcn_mfma_f32_16x16x32_bf16(af[i], bfv[j], acc[i][j], 0, 0, 0);
    }
  }
  const int cr = (lane >> 4) * 4, cc2 = lane & 15;
#pragma unroll
  for (int i = 0; i < 2; ++i)
#pragma unroll
    for (int j = 0; j < N / 16; ++j)
#pragma unroll
      for (int q = 0; q < 4; ++q) {
        int row = m0 + wm + i * 16 + cr + q;
        int col = j * 16 + cc2;
        float v = acc[i][j][q];
        if (ACT == 1) v = tanhf(v);
        else if (ACT == 2) v = 1.f / (1.f + expf(-v));
        out[(size_t)row * N + col] = f2bf(v);
      }
}

// merged down-GEMMs: 256 blocks (4 groups x 64 m-tiles), all prepacked mixes
__global__ __launch_bounds__(256, 2) void k_down4(
    const unsigned short* __restrict__ XMw, const unsigned short* __restrict__ XMa,
    const unsigned short* __restrict__ XMv, const unsigned short* __restrict__ XMg,
    const unsigned short* __restrict__ W1T, const unsigned short* __restrict__ A1T,
    const unsigned short* __restrict__ V1T, const unsigned short* __restrict__ G1T,
    unsigned short* __restrict__ HWB, unsigned short* __restrict__ HAB,
    unsigned short* __restrict__ HVB, unsigned short* __restrict__ HGB) {
  __shared__ __align__(16) unsigned short As[128][64];
  __shared__ __align__(16) unsigned short Bs[128][64];
  int g = blockIdx.x >> 6;
  int m0 = (blockIdx.x & 63) * 128;
  if (g == 0)      down_body<64, 1>(m0, As, Bs, XMw, W1T, HWB);
  else if (g == 1) down_body<64, 0>(m0, As, Bs, XMa, A1T, HAB);
  else if (g == 2) down_body<32, 0>(m0, As, Bs, XMv, V1T, HVB);
  else             down_body<128, 2>(m0, As, Bs, XMg, G1T, HGB);
}

// ---------------- up GEMM (K in {32,64,128}), single K pass ----------------
// MODE 0: wd = exp(-exp(-softplus(-(bias+up)) - 0.5)) -> outF (f32)
// MODE 1: sigmoid(bias+up) -> outB (bf16)
// MODE 3: up -> outB (bf16)
template <int K, int MODE>
__global__ __launch_bounds__(256, 2) void k_up(
    const unsigned short* __restrict__ A, const unsigned short* __restrict__ Bt,
    const float* __restrict__ bias, float* __restrict__ outF,
    unsigned short* __restrict__ outB) {
  __shared__ __align__(16) unsigned short As[128][K];
  __shared__ __align__(16) unsigned short Bs[128][K];
  const int tid = threadIdx.x, lane = tid & 63, wv = tid >> 6;
  const int m0 = blockIdx.y * 128, n0 = blockIdx.x * 128;
  const int wm = (wv >> 1) * 64, wn = (wv & 1) * 64;
  constexpr int LPR = K / 8;
  constexpr int RPC = 64 / LPR;
  const int lr = lane / LPR, lc = (lane % LPR) * 8;
  f32x4 acc[4][4] = {};
#pragma unroll
  for (int i = 0; i < K / 16; ++i) {
    int chunk = wv * (K / 16) + i;
    int r = chunk * RPC + lr;
    gl16(A + (size_t)(m0 + r) * K + lc, (char*)&As[0][0] + chunk * 1024);
    gl16(Bt + (size_t)(n0 + r) * K + lc, (char*)&Bs[0][0] + chunk * 1024);
  }
  __syncthreads();
  const int rr = lane & 15;
#pragma unroll
  for (int ks = 0; ks < K / 32; ++ks) {
    const int kof = ks * 32 + (lane >> 4) * 8;
    bf16x8 af[4], bfv[4];
#pragma unroll
    for (int i = 0; i < 4; ++i) af[i] = *(const bf16x8*)&As[wm + i * 16 + rr][kof];
#pragma unroll
    for (int j = 0; j < 4; ++j) bfv[j] = *(const bf16x8*)&Bs[wn + j * 16 + rr][kof];
#pragma unroll
    for (int i = 0; i < 4; ++i)
#pragma unroll
      for (int j = 0; j < 4; ++j)
        acc[i][j] = __builtin_amdgcn_mfma_f32_16x16x32_bf16(af[i], bfv[j], acc[i][j], 0, 0, 0);
  }
  const int cr = (lane >> 4) * 4, cc2 = lane & 15;
#pragma unroll
  for (int i = 0; i < 4; ++i)
#pragma unroll
    for (int j = 0; j < 4; ++j)
#pragma unroll
      for (int q = 0; q < 4; ++q) {
        int row = m0 + wm + i * 16 + cr + q;
        int col = n0 + wn + j * 16 + cc2;
        size_t off = (size_t)row * C_ + col;
        float up = acc[i][j][q];
        if (MODE == 0) {
          float z = -(bias[col] + up);
          float sp = fmaxf(z, 0.f) + log1pf(expf(-fabsf(z)));
          outF[off] = expf(-expf(-sp - 0.5f));
        } else if (MODE == 1) {
          outB[off] = f2bf(1.f / (1.f + expf(-(bias[col] + up))));
        } else {
          outB[off] = f2bf(up);
        }
      }
}

// ---------------- WKV recurrent scan: LDS pipeline + 1-step reg prefetch -------
// R12 structure with the serializer removed: no sched_barrier; per position
// {ISSUE(t+4) -> vmcnt(12) -> PREF(regs <- slot t+1) -> COMPUTE(t) on regs
// loaded last position}. The asm "memory" clobber orders the ds_reads (memory
// ops can't hoist); VALU floats freely, so step t's compute hides step t+1's
// ds_read latency and the vmcnt wait. vmcnt(12): queue <= 19 (16 loads + <=3
// stores), draining to 12 always covers slot t+1's 4 loads (exact for peeled
// iters 0..2 as well). Two named register sets ping-pong via x8 unroll
// (rule #20: all indices compile-time). (64,2): keep both sets un-collapsed.
__global__ __launch_bounds__(64, 2) void k_scan(
    const unsigned short* __restrict__ RB, const float* __restrict__ WD,
    const unsigned short* __restrict__ KB, const unsigned short* __restrict__ VB,
    const unsigned short* __restrict__ AHB, const unsigned short* __restrict__ BHB,
    const float* __restrict__ s0, float* __restrict__ out) {
  __shared__ __align__(16) char sl[8][1024];
  const int lane = threadIdx.x & 63;
  const int p = blockIdx.x;
  const int wq = p >> 7, bh = p & 127;
  const int b = bh >> 5, h = bh & 31;
  const int e = lane & 15, rl = lane >> 4;
  const int row = wq * 4 + rl;
  const size_t base = (size_t)b * T_ * C_ + h * 64;
  f32x4 S = *(const f32x4*)(s0 + ((size_t)(b * H_ + h) * 64 + row) * 64 + e * 4);

  // hoisted per-lane source bases (stream select + lane offset are invariant)
  const char* srcA = (lane < 32 ? (const char*)RB : (const char*)KB) + (lane & 31) * 4;
  const char* srcB = (lane < 32 ? (const char*)AHB : (const char*)BHB) + (lane & 31) * 4;
  const char* srcW = (const char*)WD + lane * 4;
  const char* srcV = (const char*)VB + lane * 4;

  bf16x4 rv0, kv0, av0, bv0, rv1, kv1, av1, bv1;
  f32x4 wv0, wv1;
  unsigned short vi0, vi1;

#define ISSUE(t, slot)                                                        \
  {                                                                           \
    size_t ti = (size_t)((t) < T_ ? (t) : T_ - 1);                            \
    size_t eo = base + ti * C_;                                               \
    char* d = &sl[(slot)][0];                                                 \
    gl4(srcA + 2 * eo, d);                                                    \
    gl4(srcB + 2 * eo, d + 256);                                              \
    gl4(srcW + 4 * eo, d + 512);                                              \
    gl4(srcV + 2 * eo, d + 768);                                              \
  }

#define PREF(n, slot)                                                         \
  {                                                                           \
    const char* bp = &sl[(slot)][0];                                          \
    rv##n = *(const bf16x4*)(bp + e * 8);                                     \
    kv##n = *(const bf16x4*)(bp + 128 + e * 8);                               \
    av##n = *(const bf16x4*)(bp + 256 + e * 8);                               \
    bv##n = *(const bf16x4*)(bp + 384 + e * 8);                               \
    wv##n = *(const f32x4*)(bp + 512 + e * 16);                               \
    vi##n = *(const unsigned short*)(bp + 768 + row * 2);                     \
  }

#define COMPUTE(n, t)                                                         \
  {                                                                           \
    float rr[4], kk[4], aa[4], bb[4];                                         \
    _Pragma("unroll") for (int j = 0; j < 4; ++j) {                           \
      rr[j] = (float)rv##n[j];                                                \
      kk[j] = (float)kv##n[j];                                                \
      aa[j] = (float)av##n[j];                                                \
      bb[j] = (float)bv##n[j];                                                \
    }                                                                         \
    float sa = S[0] * aa[0];                                                  \
    sa = fmaf(S[1], aa[1], sa);                                               \
    sa = fmaf(S[2], aa[2], sa);                                               \
    sa = fmaf(S[3], aa[3], sa);                                               \
    sa = rsum16(sa);                                                          \
    float vi = bf2f(vi##n);                                                   \
    float o = 0.f;                                                            \
    _Pragma("unroll") for (int j = 0; j < 4; ++j) {                           \
      S[j] = fmaf(S[j], wv##n[j], fmaf(sa, bb[j], vi * kk[j]));               \
      o = fmaf(S[j], rr[j], o);                                               \
    }                                                                         \
    o = rsum16(o);                                                            \
    if (e == 0) out[base + (size_t)(t) * C_ + row] = o;                       \
  }

#define VMW asm volatile("s_waitcnt vmcnt(12)" ::: "memory")

  ISSUE(0, 0) ISSUE(1, 1) ISSUE(2, 2) ISSUE(3, 3)
  VMW;           // drains L_0 (16 outstanding -> 12)
  PREF(0, 0)     // regs set0 = step 0 operands
#pragma unroll 1
  for (int t = 0; t < T_; t += 8) {
    ISSUE(t + 4, 4)  VMW; PREF(1, 1) COMPUTE(0, t + 0)
    ISSUE(t + 5, 5)  VMW; PREF(0, 2) COMPUTE(1, t + 1)
    ISSUE(t + 6, 6)  VMW; PREF(1, 3) COMPUTE(0, t + 2)
    ISSUE(t + 7, 7)  VMW; PREF(0, 4) COMPUTE(1, t + 3)
    ISSUE(t + 8, 0)  VMW; PREF(1, 5) COMPUTE(0, t + 4)
    ISSUE(t + 9, 1)  VMW; PREF(0, 6) COMPUTE(1, t + 5)
    ISSUE(t + 10, 2) VMW; PREF(1, 7) COMPUTE(0, t + 6)
    ISSUE(t + 11, 3) VMW; PREF(0, 0) COMPUTE(1, t + 7)
  }
#undef ISSUE
#undef PREF
#undef COMPUTE
#undef VMW
}

// ---------------- GroupNorm + bonus + gate (wave per (b,t,h)) ----------------
__global__ __launch_bounds__(256) void k_gn(
    const float* __restrict__ o, const unsigned short* __restrict__ rb,
    const unsigned short* __restrict__ kb, const unsigned short* __restrict__ v,
    const unsigned short* __restrict__ g, const float* __restrict__ r_k,
    const float* __restrict__ lnw, const float* __restrict__ lnb,
    unsigned short* __restrict__ outg) {
  int wid = blockIdx.x * 4 + (threadIdx.x >> 6);
  int lane = threadIdx.x & 63;
  int h = wid & (H_ - 1);
  size_t bt = (size_t)(wid >> 5);
  size_t off = bt * C_ + h * 64 + lane;
  int c = h * 64 + lane;
  float x = o[off];
  float mu = x;
#pragma unroll
  for (int m = 1; m < 64; m <<= 1) mu += __shfl_xor(mu, m);
  mu *= (1.f / 64.f);
  float d = x - mu;
  float var = d * d;
#pragma unroll
  for (int m = 1; m < 64; m <<= 1) var += __shfl_xor(var, m);
  var *= (1.f / 64.f);
  float y = d * rsqrtf(var + 6.4e-4f) * lnw[c] + lnb[c];
  float bd = bf2f(rb[off]) * bf2f(kb[off]) * r_k[c];
#pragma unroll
  for (int m = 1; m < 64; m <<= 1) bd += __shfl_xor(bd, m);
  float res = (y + bd * bf2f(v[off])) * bf2f(g[off]);
  outg[off] = f2bf(res);
}

// ---------------- host launch ----------------
extern "C" void kernel_launch(void* const* d_in, const int* in_sizes, int n_in,
                              void* d_out, int out_size, void* d_ws, size_t ws_size,
                              hipStream_t stream) {
  const float* x      = (const float*)d_in[0];
  const float* vfirst = (const float*)d_in[1];
  const float* xprev  = (const float*)d_in[2];
  const float* wkv0   = (const float*)d_in[3];
  const float* x_r = (const float*)d_in[4];
  const float* x_w = (const float*)d_in[5];
  const float* x_k = (const float*)d_in[6];
  const float* x_v = (const float*)d_in[7];
  const float* x_a = (const float*)d_in[8];
  const float* x_g = (const float*)d_in[9];
  const float* w0 = (const float*)d_in[10];
  const float* w1 = (const float*)d_in[11];
  const float* w2 = (const float*)d_in[12];
  const float* a0 = (const float*)d_in[13];
  const float* a1 = (const float*)d_in[14];
  const float* a2 = (const float*)d_in[15];
  const float* v0 = (const float*)d_in[16];
  const float* v1 = (const float*)d_in[17];
  const float* v2 = (const float*)d_in[18];
  const float* g1 = (const float*)d_in[19];
  const float* g2 = (const float*)d_in[20];
  const float* k_k = (const float*)d_in[21];
  const float* k_a = (const float*)d_in[22];
  const float* r_k = (const float*)d_in[23];
  const float* Wr = (const float*)d_in[24];
  const float* Wk = (const float*)d_in[25];
  const float* Wv = (const float*)d_in[26];
  const float* Wo = (const float*)d_in[27];
  const float* lnw = (const float*)d_in[28];
  const float* lnb = (const float*)d_in[29];
  float* out = (float*)d_out;
  char* ws = (char*)d_ws;

  // ---- workspace layout (~239 MiB + pad) ----
  size_t woff = 0;
  auto alloc = [&](size_t n) { char* p = ws + woff; woff += n; return p; };
  char* R1 = alloc(67108864);                       // ABF|SVB -> WD (f32)
  unsigned short* ABF = (unsigned short*)R1;
  unsigned short* SVB = (unsigned short*)(R1 + 33554432);
  float* WD = (float*)R1;
  unsigned short* WT  = (unsigned short*)alloc(8388608);   // transposed big weight
  unsigned short* W1T = (unsigned short*)alloc(262144);
  unsigned short* A1T = (unsigned short*)alloc(262144);
  unsigned short* V1T = (unsigned short*)alloc(131072);
  unsigned short* G1T = (unsigned short*)alloc(524288);
  unsigned short* W2T = (unsigned short*)alloc(262144);
  unsigned short* A2T = (unsigned short*)alloc(262144);
  unsigned short* V2T = (unsigned short*)alloc(131072);
  unsigned short* G2T = (unsigned short*)alloc(524288);
  unsigned short* HWB = (unsigned short*)alloc(1048576);
  unsigned short* HAB = (unsigned short*)alloc(1048576);
  unsigned short* HVB = (unsigned short*)alloc(524288);
  unsigned short* HGB = (unsigned short*)alloc(2097152);
  unsigned short* RB  = (unsigned short*)alloc(33554432);
  unsigned short* KB  = (unsigned short*)alloc(33554432);
  unsigned short* VB  = (unsigned short*)alloc(33554432);
  unsigned short* AHB = (unsigned short*)alloc(33554432);
  unsigned short* BHB = (unsigned short*)alloc(33554432);
  alloc(65536);  // safety pad (scan prefetch over-read)
  // Temporal overlays (regions dead at the time of each use):
  unsigned short* XMr = VB;                   // dead once V-GEMM writes VB
  unsigned short* XMv = KB;                   // dead once K-GEMM writes KB
  unsigned short* XMk = (unsigned short*)out; // d_out free until scan writes out
  unsigned short* XMw = AHB;                  // dead once K-GEMM writes AHB (down4 done)
  unsigned short* XMa = BHB;                  // dead once K-GEMM writes BHB (down4 done)
  unsigned short* XMg = RB;                   // dead once R-GEMM writes RB (down4 done)
  unsigned short* GBF  = AHB;                 // post-scan overlay (AHB dead)
  unsigned short* OUTG = BHB;                 // post-scan overlay (BHB dead)

  dim3 blk(256);
  dim3 gg(16, 64);
  dim3 g1d(1024);

  // all small weight transposes in one launch
  k_transpose8<<<dim3(1152), blk, 0, stream>>>(w1, W1T, a1, A1T, v1, V1T, g1, G1T,
                                               w2, W2T, a2, A2T, v2, V2T, g2, G2T);

  // mix prep: x read once -> all 6 mixes (XMk in d_out, XMw/XMa/XMg overlays)
  k_prep6<<<dim3(M_), blk, 0, stream>>>(x, xprev, x_r, x_v, x_k, x_w, x_a, x_g,
                                        XMr, XMv, XMk, XMw, XMa, XMg);

  // merged down-GEMMs (w,a,v,g), all prepacked bf16 mixes
  k_down4<<<dim3(256), blk, 0, stream>>>(XMw, XMa, XMv, XMg,
                                         W1T, A1T, V1T, G1T, HWB, HAB, HVB, HGB);

  // up-GEMMs needed before projections
  k_up<64, 1><<<gg, blk, 0, stream>>>(HAB, A2T, a0, nullptr, ABF);
  k_up<32, 1><<<gg, blk, 0, stream>>>(HVB, V2T, v0, nullptr, SVB);

  // R projection (XMr in VB region; writes RB, killing XMg)
  k_transpose<<<dim3(64, 64), blk, 0, stream>>>(Wr, WT, 2048, 2048);
  k_gemm_big<0><<<g1d, blk, 0, stream>>>(XMr, WT,
      nullptr, RB, nullptr, nullptr, nullptr, nullptr, nullptr, nullptr, nullptr);

  // V projection (reads XMv from KB region + SVB; writes VB, killing XMr)
  k_transpose<<<dim3(64, 64), blk, 0, stream>>>(Wv, WT, 2048, 2048);
  k_gemm_big<1><<<g1d, blk, 0, stream>>>(XMv, WT,
      nullptr, VB, SVB, vfirst, nullptr, nullptr, nullptr, nullptr, nullptr);

  // K projection (reads XMk from d_out; writes KB killing XMv, AHB killing XMw,
  // BHB killing XMa)
  k_transpose<<<dim3(64, 64), blk, 0, stream>>>(Wk, WT, 2048, 2048);
  k_gemm_big<2><<<g1d, blk, 0, stream>>>(XMk, WT,
      nullptr, KB, nullptr, nullptr, ABF, k_k, k_a, AHB, BHB);

  // w-chain up (WD overlays ABF+SVB, both consumed)
  k_up<64, 0><<<gg, blk, 0, stream>>>(HWB, W2T, w0, WD, nullptr);

  // recurrent scan -> out[b,t,c] f32 in d_out (XMk already consumed)
  k_scan<<<dim3(2048), dim3(64), 0, stream>>>(RB, WD, KB, VB, AHB, BHB, wkv0, out);

  // g-chain up (GBF overlays AHB)
  k_up<128, 3><<<gg, blk, 0, stream>>>(HGB, G2T, nullptr, nullptr, GBF);

  // GroupNorm + bonus + gate (OUTG overlays BHB)
  k_gn<<<dim3(65536), blk, 0, stream>>>(out, RB, KB, VB, GBF, r_k, lnw, lnb, OUTG);

  // final projection (overwrites d_out with the real output)
  k_transpose<<<dim3(64, 64), blk, 0, stream>>>(Wo, WT, 2048, 2048);
  k_gemm_big<3><<<g1d, blk, 0, stream>>>(OUTG, WT,
      out, nullptr, nullptr, nullptr, nullptr, nullptr, nullptr, nullptr, nullptr);
}